// Round 4
// baseline (560.104 us; speedup 1.0000x reference)
//
#include <hip/hip_runtime.h>

#define TB 8
#define TC 64
#define TT 300
#define TDD 161
#define TH 128
#define TO 64
#define TN (TB * TDD)          // 1288 sequences
#define TWOH 256
#define TILE 16
#define NBLK 81                // ceil(1288/16)
#define ODCH (TO * TDD)        // 10304 channels
#define TOTAL (TB * TO * TT * TDD)      // 24729600
#define AFRAG (4 * 4 * 16 * 8)          // 2048 ushorts: h-only A frags (K=128)
#define PRE_SLOT_U2 (NBLK * 256 * 4)    // 82944 uint2 per timestep

typedef __attribute__((ext_vector_type(8))) short bf16x8;
typedef __attribute__((ext_vector_type(4))) float f32x4;

#define MFMA __builtin_amdgcn_mfma_f32_16x16x32_bf16

__device__ __forceinline__ ushort f2bf(float f) {
  union { float f; unsigned u; } v; v.f = f;
  return (ushort)((v.u + 0x7fffu + ((v.u >> 16) & 1u)) >> 16);  // RNE
}
__device__ __forceinline__ float bflo(unsigned u) {
  union { unsigned u; float f; } v; v.u = u << 16; return v.f;
}
__device__ __forceinline__ float bfhi(unsigned u) {
  union { unsigned u; float f; } v; v.u = u & 0xffff0000u; return v.f;
}

// k-mapping inside a 16x16x32 fragment; identical convention everywhere so any
// permutation error cancels in the contraction (verified R1/R2).
__device__ __forceinline__ int kmap(int e, int q) {
  return ((e < 4) ? 0 : 16) + q * 4 + (e & 3);
}
// Swizzled ushort index of (row, kg) in the h A-frag buffer (kg in [0,128)).
__device__ __forceinline__ int aidx_sw(int row, int kg) {
  int ks = kg >> 5, k32 = kg & 31;
  int half = k32 >> 4, qq = (k32 >> 2) & 3, em = k32 & 3;
  int B = (ks * 4 + qq) * 16 + (row ^ qq);
  return B * 8 + half * 4 + em;
}

// ---------------- prepass: pre[t] = x_t @ Wx + b  (bf16, blocked layout) ----
__global__ __launch_bounds__(256) void prepass_kernel(
    const float* __restrict__ x, const float* __restrict__ Wx,
    const float* __restrict__ bias, ushort* __restrict__ pre, int t0)
{
  const int blk = blockIdx.x, slot = blockIdx.y;
  const int t = t0 + slot;
  const int tid = threadIdx.x;
  const int w = tid >> 6, l = tid & 63, q = l >> 4, r = l & 15;
  int n = blk * 16 + r;
  int ok = (n < TN);
  int b = ok ? (n / TDD) : 0;
  int d = ok ? (n - b * TDD) : 0;
  const int xrow = (b * TC) * (TT * TDD) + t * TDD + d;

  bf16x8 afx[2];
  #pragma unroll
  for (int ks = 0; ks < 2; ks++) {
    bf16x8 f;
    #pragma unroll
    for (int e = 0; e < 8; e++)
      f[e] = (short)f2bf(x[xrow + (ks * 32 + kmap(e, q)) * (TT * TDD)]);
    afx[ks] = f;
  }
  uint2* preu2 = (uint2*)pre;
  #pragma unroll
  for (int jj = 0; jj < 4; jj++) {
    int col = w * 64 + jj * 16 + r;
    bf16x8 f0, f1;
    #pragma unroll
    for (int e = 0; e < 8; e++) {
      f0[e] = (short)f2bf(Wx[kmap(e, q) * TWOH + col]);
      f1[e] = (short)f2bf(Wx[(32 + kmap(e, q)) * TWOH + col]);
    }
    float bv = bias[col];
    f32x4 a = {bv, bv, bv, bv};
    a = MFMA(afx[0], f0, a, 0, 0, 0);
    a = MFMA(afx[1], f1, a, 0, 0, 0);
    uint2 pv;
    pv.x = (unsigned)f2bf(a[0]) | ((unsigned)f2bf(a[1]) << 16);
    pv.y = (unsigned)f2bf(a[2]) | ((unsigned)f2bf(a[3]) << 16);
    preu2[((slot * NBLK + blk) * 256 + col) * 4 + q] = pv;
  }
}

// ---------------- recurrent kernel --------------------------------------
__global__ __launch_bounds__(512) void gru_kernel(
    const int* __restrict__ lengths, const float* __restrict__ Wh,
    const float* __restrict__ Wo, const float* __restrict__ bo,
    const uint2* __restrict__ preu, float* __restrict__ yout,
    float* __restrict__ wsH, float* __restrict__ wsStats,
    int t0, int t1, int last)
{
  __shared__ __align__(16) ushort ldsA[2][AFRAG];
  __shared__ int s_b[TILE], s_d[TILE], s_len[TILE], s_ok[TILE];

  const int tid = threadIdx.x;
  const int w = tid >> 6, l = tid & 63, q = l >> 4, r = l & 15;
  const int rxq = r ^ q;
  const int blk = blockIdx.x;

  if (tid < TILE) {
    int n = blk * TILE + tid;
    int ok = (n < TN) ? 1 : 0;
    int b = ok ? (n / TDD) : 0;
    int d = ok ? (n - b * TDD) : 0;
    s_b[tid] = b; s_d[tid] = d; s_ok[tid] = ok;
    s_len[tid] = ok ? lengths[b] : -1;
  }
  __syncthreads();

  const int ucol = w * 16 + r;          // hidden unit this lane owns
  // gate B-frags from Wh (registers, once)
  bf16x8 wf[2][4];
  #pragma unroll
  for (int jj = 0; jj < 2; jj++) {
    int col = jj * TH + ucol;
    #pragma unroll
    for (int ks = 0; ks < 4; ks++) {
      bf16x8 f;
      #pragma unroll
      for (int e = 0; e < 8; e++)
        f[e] = (short)f2bf(Wh[(ks * 32 + kmap(e, q)) * TWOH + col]);
      wf[jj][ks] = f;
    }
  }
  // y B-frags (all 8 waves; groups alternate t-parity)
  const bool ywave = (w < 4);
  const int o = (w & 3) * 16 + r;
  bf16x8 wo[4];
  #pragma unroll
  for (int ks = 0; ks < 4; ks++) {
    bf16x8 f;
    #pragma unroll
    for (int e = 0; e < 8; e++)
      f[e] = (short)f2bf(Wo[(ks * 32 + kmap(e, q)) * TO + o]);
    wo[ks] = f;
  }
  const float bo_v = bo[o];

  int llen[4], lok[4], ld_[4], ybase[4];
  #pragma unroll
  for (int i = 0; i < 4; i++) {
    int nn = q * 4 + i;
    llen[i] = s_len[nn]; lok[i] = s_ok[nn]; ld_[i] = s_d[nn];
    ybase[i] = (s_b[nn] * TO + o) * (TT * TDD) + s_d[nn];
  }
  float ysum[4] = {0, 0, 0, 0}, ysq[4] = {0, 0, 0, 0};

  // h state + LDS write indices
  float hreg[4];
  int hwi[4];
  #pragma unroll
  for (int i = 0; i < 4; i++) hwi[i] = aidx_sw(q * 4 + i, ucol);
  if (t0 == 0) {
    #pragma unroll
    for (int i = 0; i < 4; i++) hreg[i] = 0.0f;
    for (int i = tid; i < AFRAG; i += 512) ldsA[0][i] = 0;
  } else {
    const float* hp = &wsH[(blk * TH + ucol) * 16 + q * 4];
    #pragma unroll
    for (int i = 0; i < 4; i++) {
      hreg[i] = hp[i];
      ldsA[0][hwi[i]] = f2bf(hreg[i]);
    }
  }
  __syncthreads();

  // pre-stream addressing (uint2 units)
  const int zbase = (blk * 256 + ucol) * 4 + q;
  const int cbase = zbase + TH * 4;
  const int smax = t1 - 1 - t0;
  uint2 z0, z1, z2, z3, c0, c1, c2, c3;
  {
    int s0_ = 0, s1_ = smax < 1 ? smax : 1, s2_ = smax < 2 ? smax : 2, s3_ = smax < 3 ? smax : 3;
    z0 = preu[s0_ * PRE_SLOT_U2 + zbase]; c0 = preu[s0_ * PRE_SLOT_U2 + cbase];
    z1 = preu[s1_ * PRE_SLOT_U2 + zbase]; c1 = preu[s1_ * PRE_SLOT_U2 + cbase];
    z2 = preu[s2_ * PRE_SLOT_U2 + zbase]; c2 = preu[s2_ * PRE_SLOT_U2 + cbase];
    z3 = preu[s3_ * PRE_SLOT_U2 + zbase]; c3 = preu[s3_ * PRE_SLOT_U2 + cbase];
  }

#define GBODY(T_, PAR, UZ, UC, NZ, NC)                                         \
  {                                                                            \
    const int t_ = (T_);                                                       \
    int sN = t_ - t0 + 4; if (sN > smax) sN = smax;                            \
    NZ = preu[sN * PRE_SLOT_U2 + zbase];                                       \
    NC = preu[sN * PRE_SLOT_U2 + cbase];                                       \
    const ushort* Ab = ldsA[PAR];                                              \
    bf16x8 af0 = *(const bf16x8*)&Ab[((0 * 4 + q) * 16 + rxq) * 8];            \
    bf16x8 af1 = *(const bf16x8*)&Ab[((1 * 4 + q) * 16 + rxq) * 8];            \
    bf16x8 af2 = *(const bf16x8*)&Ab[((2 * 4 + q) * 16 + rxq) * 8];            \
    bf16x8 af3 = *(const bf16x8*)&Ab[((3 * 4 + q) * 16 + rxq) * 8];            \
    f32x4 az  = {bflo(UZ.x), bfhi(UZ.x), bflo(UZ.y), bfhi(UZ.y)};              \
    f32x4 ac  = {bflo(UC.x), bfhi(UC.x), bflo(UC.y), bfhi(UC.y)};              \
    f32x4 az2 = {0, 0, 0, 0}, ac2 = {0, 0, 0, 0};                              \
    az  = MFMA(af0, wf[0][0], az,  0, 0, 0);                                   \
    az2 = MFMA(af1, wf[0][1], az2, 0, 0, 0);                                   \
    ac  = MFMA(af0, wf[1][0], ac,  0, 0, 0);                                   \
    ac2 = MFMA(af1, wf[1][1], ac2, 0, 0, 0);                                   \
    az  = MFMA(af2, wf[0][2], az,  0, 0, 0);                                   \
    az2 = MFMA(af3, wf[0][3], az2, 0, 0, 0);                                   \
    ac  = MFMA(af2, wf[1][2], ac,  0, 0, 0);                                   \
    ac2 = MFMA(af3, wf[1][3], ac2, 0, 0, 0);                                   \
    if (((PAR) ? ywave : !ywave) && t_ > 0) {                                  \
      f32x4 ya = {bo_v, bo_v, bo_v, bo_v}, yb = {0, 0, 0, 0};                  \
      ya = MFMA(af0, wo[0], ya, 0, 0, 0);                                      \
      yb = MFMA(af1, wo[1], yb, 0, 0, 0);                                      \
      ya = MFMA(af2, wo[2], ya, 0, 0, 0);                                      \
      yb = MFMA(af3, wo[3], yb, 0, 0, 0);                                      \
      const int tm = t_ - 1;                                                   \
      _Pragma("unroll")                                                        \
      for (int i = 0; i < 4; i++) {                                            \
        if (lok[i] && tm < llen[i]) {                                          \
          float v = ya[i] + yb[i];                                             \
          yout[ybase[i] + tm * TDD] = v;                                       \
          ysum[i] += v; ysq[i] += v * v;                                       \
        }                                                                      \
      }                                                                        \
    }                                                                          \
    ushort hb[4];                                                              \
    _Pragma("unroll")                                                          \
    for (int i = 0; i < 4; i++) {                                              \
      float a_  = az[i] + az2[i];                                              \
      float b_  = ac[i] + ac2[i];                                              \
      float zv  = __builtin_amdgcn_rcpf(1.0f + __expf(-a_));                   \
      float hc  = 1.0f - 2.0f * __builtin_amdgcn_rcpf(1.0f + __expf(2.0f * b_)); \
      float h   = zv * hreg[i] + (1.0f - zv) * hc;                             \
      hreg[i] = (t_ < llen[i]) ? h : hreg[i];                                  \
      hb[i] = f2bf(hreg[i]);                                                   \
    }                                                                          \
    ushort* Aw = ldsA[(PAR) ^ 1];                                              \
    Aw[hwi[0]] = hb[0]; Aw[hwi[1]] = hb[1];                                    \
    Aw[hwi[2]] = hb[2]; Aw[hwi[3]] = hb[3];                                    \
    __syncthreads();                                                           \
  }

  for (int t = t0; t < t1; t += 2) {
    uint2 nz0, nc0, nz1, nc1;
    GBODY(t,     0, z0, c0, nz0, nc0)
    GBODY(t + 1, 1, z1, c1, nz1, nc1)
    z0 = z2; c0 = c2; z1 = z3; c1 = c3;
    z2 = nz0; c2 = nc0; z3 = nz1; c3 = nc1;
  }
#undef GBODY

  // epilogue: y_{t1-1} (tm odd=299 when last) by the !ywave group
  if (last && !ywave) {
    const ushort* Ab = ldsA[0];   // t1 even -> h_{t1-1} is in buffer 0
    bf16x8 af0 = *(const bf16x8*)&Ab[((0 * 4 + q) * 16 + rxq) * 8];
    bf16x8 af1 = *(const bf16x8*)&Ab[((1 * 4 + q) * 16 + rxq) * 8];
    bf16x8 af2 = *(const bf16x8*)&Ab[((2 * 4 + q) * 16 + rxq) * 8];
    bf16x8 af3 = *(const bf16x8*)&Ab[((3 * 4 + q) * 16 + rxq) * 8];
    f32x4 ya = {bo_v, bo_v, bo_v, bo_v}, yb = {0, 0, 0, 0};
    ya = MFMA(af0, wo[0], ya, 0, 0, 0);
    yb = MFMA(af1, wo[1], yb, 0, 0, 0);
    ya = MFMA(af2, wo[2], ya, 0, 0, 0);
    yb = MFMA(af3, wo[3], yb, 0, 0, 0);
    const int tm = TT - 1;
    #pragma unroll
    for (int i = 0; i < 4; i++) {
      if (lok[i] && tm < llen[i]) {
        float v = ya[i] + yb[i];
        yout[ybase[i] + tm * TDD] = v;
        ysum[i] += v; ysq[i] += v * v;
      }
    }
  }
  // checkpoint h + flush stats
  {
    float* hp = &wsH[(blk * TH + ucol) * 16 + q * 4];
    #pragma unroll
    for (int i = 0; i < 4; i++) hp[i] = hreg[i];
  }
  #pragma unroll
  for (int i = 0; i < 4; i++) {
    if (lok[i]) {
      atomicAdd(&wsStats[o * TDD + ld_[i]], ysum[i]);
      atomicAdd(&wsStats[ODCH + o * TDD + ld_[i]], ysq[i]);
    }
  }
}

// ---------------- BN finalize: per-channel scale/shift ------------------
__global__ __launch_bounds__(256) void finalize_kernel(
    const int* __restrict__ lengths, const float* __restrict__ gamma,
    const float* __restrict__ beta, float* __restrict__ wsStats)
{
  int ch = blockIdx.x * 256 + threadIdx.x;
  if (ch >= ODCH) return;
  int c = 0;
  #pragma unroll
  for (int b = 0; b < TB; b++) c += lengths[b];
  float inv = 1.0f / (float)c;
  float mean = wsStats[ch] * inv;
  float var = wsStats[ODCH + ch] * inv - mean * mean;
  float sc = rsqrtf(var + 1e-5f) * gamma[ch];
  wsStats[2 * ODCH + ch] = sc;
  wsStats[3 * ODCH + ch] = beta[ch] - mean * sc;
}

// ---------------- normalize (float4, scale/shift table) ------------------
__global__ __launch_bounds__(256) void norm_kernel(
    const int* __restrict__ lengths, const float* __restrict__ ss,
    float* __restrict__ out)
{
  int i4 = blockIdx.x * 256 + threadIdx.x;   // TOTAL/4 elements, exact grid
  int idx = i4 * 4;
  float vv[4];
  *(float4*)vv = ((const float4*)out)[i4];
  int dq = idx / TDD; int d = idx - dq * TDD;
  int tq = dq / TT;   int tt = dq - tq * TT;
  int o = tq & 63;    int b = tq >> 6;
  float res[4];
  #pragma unroll
  for (int k = 0; k < 4; k++) {
    int ch = o * TDD + d;
    float r_ = 0.0f;
    if (tt < lengths[b])
      r_ = vv[k] * ss[ch] + ss[ODCH + ch];
    res[k] = r_;
    d++;
    if (d == TDD) { d = 0; tt++; if (tt == TT) { tt = 0; o++; if (o == 64) { o = 0; b++; } } }
  }
  ((float4*)out)[i4] = *(float4*)res;
}

extern "C" void kernel_launch(void* const* d_in, const int* in_sizes, int n_in,
                              void* d_out, int out_size, void* d_ws, size_t ws_size,
                              hipStream_t stream)
{
  const float* x       = (const float*)d_in[0];
  const int*   lengths = (const int*)d_in[1];
  const float* Wx      = (const float*)d_in[2];
  const float* Wh      = (const float*)d_in[3];
  const float* bias    = (const float*)d_in[4];
  const float* Wo      = (const float*)d_in[5];
  const float* bo      = (const float*)d_in[6];
  const float* gamma   = (const float*)d_in[7];
  const float* beta    = (const float*)d_in[8];
  float* out = (float*)d_out;

  float* ws = (float*)d_ws;
  float* wsStats = ws;                                  // 4*ODCH floats
  float* wsH = ws + 4 * ODCH;                           // 81*128*16 floats
  ushort* pre = (ushort*)(ws + 4 * ODCH + NBLK * TH * 16);
  const size_t fixed_b = (size_t)(4 * ODCH + NBLK * TH * 16) * 4;
  const size_t per_t = (size_t)NBLK * 256 * 16 * 2;     // 663552 B per timestep

  int tch = TT;
  size_t avail = ws_size > fixed_b ? ws_size - fixed_b : 0;
  size_t maxT = avail / per_t;
  if (maxT < (size_t)TT) {
    tch = ((int)maxT) & ~1;
    if (tch < 2) tch = 2;
  }

  hipMemsetAsync(wsStats, 0, 2 * ODCH * sizeof(float), stream);
  for (int T0 = 0; T0 < TT; T0 += tch) {
    int T1 = T0 + tch; if (T1 > TT) T1 = TT;
    hipLaunchKernelGGL(prepass_kernel, dim3(NBLK, T1 - T0), dim3(256), 0, stream,
                       x, Wx, bias, pre, T0);
    hipLaunchKernelGGL(gru_kernel, dim3(NBLK), dim3(512), 0, stream,
                       lengths, Wh, Wo, bo, (const uint2*)pre, out,
                       wsH, wsStats, T0, T1, (T1 == TT) ? 1 : 0);
  }
  hipLaunchKernelGGL(finalize_kernel, dim3((ODCH + 255) / 256), dim3(256), 0, stream,
                     lengths, gamma, beta, wsStats);
  hipLaunchKernelGGL(norm_kernel, dim3(TOTAL / 4 / 256), dim3(256), 0, stream,
                     lengths, wsStats + 2 * ODCH, out);
}

// Round 5
// 310.568 us; speedup vs baseline: 1.8035x; 1.8035x over previous
//
#include <hip/hip_runtime.h>

#define TB 8
#define TC 64
#define TT 300
#define TDD 161
#define TH 128
#define TO 64
#define TN (TB * TDD)          // 1288 sequences
#define TWOH 256
#define TILE 16
#define NBLK 81                // ceil(1288/16)
#define NKS 6                  // (C+H)/32
#define ODCH (TO * TDD)        // 10304 channels
#define TOTAL (TB * TO * TT * TDD)      // 24729600
#define AFRAG (NKS * 4 * 16 * 8)        // 3072 ushorts per A-frag buffer

typedef __attribute__((ext_vector_type(8))) short bf16x8;
typedef __attribute__((ext_vector_type(4))) float f32x4;

#define MFMA __builtin_amdgcn_mfma_f32_16x16x32_bf16

__device__ __forceinline__ ushort f2bf(float f) {
  union { float f; unsigned u; } v; v.f = f;
  return (ushort)((v.u + 0x7fffu + ((v.u >> 16) & 1u)) >> 16);  // RNE
}

// k-mapping inside a 16x16x32 fragment; identical convention for A and B so
// any permutation error cancels in the contraction (verified R1/R2/R4).
__device__ __forceinline__ int kmap(int e, int q) {
  return ((e < 4) ? 0 : 16) + q * 4 + (e & 3);
}
// Swizzled ushort index of (row, kg) in the A-frag buffer (kg in [0,192)).
__device__ __forceinline__ int aidx_sw(int row, int kg) {
  int ks = kg >> 5, k32 = kg & 31;
  int half = k32 >> 4, qq = (k32 >> 2) & 3, em = k32 & 3;
  int B = (ks * 4 + qq) * 16 + (row ^ qq);
  return B * 8 + half * 4 + em;
}

__global__ __launch_bounds__(512) void gru_kernel(
    const float* __restrict__ x, const int* __restrict__ lengths,
    const float* __restrict__ Wx, const float* __restrict__ Wh,
    const float* __restrict__ bias, const float* __restrict__ Wo,
    const float* __restrict__ bo, float* __restrict__ yout,
    float* __restrict__ wsStats)
{
  __shared__ __align__(16) ushort ldsA[2][AFRAG];  // double-buffered [x_t | h] frags
  __shared__ int s_b[TILE], s_d[TILE], s_len[TILE], s_ok[TILE];

  const int tid = threadIdx.x;
  const int w = tid >> 6, l = tid & 63, q = l >> 4, r = l & 15;
  const int rxq = r ^ q;

  if (tid < TILE) {
    int n = blockIdx.x * TILE + tid;
    int ok = (n < TN) ? 1 : 0;
    int b = ok ? (n / TDD) : 0;
    int d = ok ? (n - b * TDD) : 0;
    s_b[tid] = b; s_d[tid] = d; s_ok[tid] = ok;
    s_len[tid] = ok ? lengths[b] : -1;
  }
  // zero the h-part (ushort idx >= 1024) of buffer 0 (h_{-1} = 0)
  for (int i = tid; i < AFRAG - 1024; i += 512) ldsA[0][1024 + i] = 0;
  __syncthreads();

  // ---- x loader mapping: thread -> (c = tid/8, nn = (tid%8)*2 + {0,1})
  const int xc = tid >> 3;
  const int xn0 = (tid & 7) * 2;
  int xok[2], xbase[2], xa[2];
  #pragma unroll
  for (int j = 0; j < 2; j++) {
    int nn = xn0 + j;
    xok[j] = s_ok[nn];
    xbase[j] = (s_b[nn] * TC + xc) * (TT * TDD) + s_d[nn];
    xa[j] = aidx_sw(nn, xc);
  }
  // x(0) into buffer 0; preload x(1..3) into the rotation (depth 4)
  #pragma unroll
  for (int j = 0; j < 2; j++) {
    float v = xok[j] ? x[xbase[j]] : 0.0f;
    ldsA[0][xa[j]] = f2bf(v);
  }
  float wx0 = xok[0] ? x[xbase[0] + 1 * TDD] : 0.0f;  // x(t+1): staged this step
  float wx1 = xok[1] ? x[xbase[1] + 1 * TDD] : 0.0f;
  float sx0 = xok[0] ? x[xbase[0] + 2 * TDD] : 0.0f;  // x(t+2)
  float sx1 = xok[1] ? x[xbase[1] + 2 * TDD] : 0.0f;
  float tx0 = xok[0] ? x[xbase[0] + 3 * TDD] : 0.0f;  // x(t+3)
  float tx1 = xok[1] ? x[xbase[1] + 3 * TDD] : 0.0f;

  // ---- gate B-fragments from [Wx; Wh] (registers, loaded once)
  // wave w owns z-col ucol and c-col 128+ucol: z,c for the SAME unit in the
  // same lane -> gates fully in-register.
  bf16x8 wf[2][NKS];
  const int ucol = w * 16 + r;
  #pragma unroll
  for (int jj = 0; jj < 2; jj++) {
    int col = jj * TH + ucol;
    #pragma unroll
    for (int ks = 0; ks < NKS; ks++) {
      bf16x8 f;
      #pragma unroll
      for (int e = 0; e < 8; e++) {
        int kg = ks * 32 + kmap(e, q);
        float v = (kg < TC) ? Wx[kg * TWOH + col] : Wh[(kg - TC) * TWOH + col];
        f[e] = (short)f2bf(v);
      }
      wf[jj][ks] = f;
    }
  }
  const float bz = bias[ucol];
  const float bc = bias[TH + ucol];

  // ---- y B-frags (all 8 waves; groups alternate t-parity), o = (w&3)*16+r
  const int o = (w & 3) * 16 + r;
  bf16x8 wo[4];
  #pragma unroll
  for (int ks = 0; ks < 4; ks++) {
    bf16x8 f;
    #pragma unroll
    for (int e = 0; e < 8; e++)
      f[e] = (short)f2bf(Wo[(ks * 32 + kmap(e, q)) * TO + o]);
    wo[ks] = f;
  }
  const float bo_v = bo[o];

  int llen[4], lok[4], ld_[4], ybase[4];
  #pragma unroll
  for (int i = 0; i < 4; i++) {
    int nn = q * 4 + i;
    llen[i] = s_len[nn]; lok[i] = s_ok[nn]; ld_[i] = s_d[nn];
    ybase[i] = (s_b[nn] * TO + o) * (TT * TDD) + s_d[nn];
  }
  float ysum[4] = {0, 0, 0, 0}, ysq[4] = {0, 0, 0, 0};

  float hreg[4] = {0, 0, 0, 0};
  int hwi[4];
  #pragma unroll
  for (int i = 0; i < 4; i++) hwi[i] = aidx_sw(q * 4 + i, TC + ucol);
  __syncthreads();

// One recurrence step. NO vmcnt drain at the barrier (T3/T4): only wait our
// own LDS ops (h/x ds_writes) before the raw s_barrier; x prefetches and y
// stores stay in flight across it. sched_barrier(0) pins any reordering.
#define STEP(T_, PAR)                                                          \
  {                                                                            \
    const int t_ = (T_);                                                       \
    int tc = t_ + 4; tc = (tc < TT) ? tc : (TT - 1);                           \
    float nx0 = xok[0] ? x[xbase[0] + tc * TDD] : 0.0f;                        \
    float nx1 = xok[1] ? x[xbase[1] + tc * TDD] : 0.0f;                        \
    const ushort* Ab = ldsA[PAR];                                              \
    bf16x8 af0 = *(const bf16x8*)&Ab[((0 * 4 + q) * 16 + rxq) * 8];            \
    bf16x8 af1 = *(const bf16x8*)&Ab[((1 * 4 + q) * 16 + rxq) * 8];            \
    bf16x8 af2 = *(const bf16x8*)&Ab[((2 * 4 + q) * 16 + rxq) * 8];            \
    bf16x8 af3 = *(const bf16x8*)&Ab[((3 * 4 + q) * 16 + rxq) * 8];            \
    bf16x8 af4 = *(const bf16x8*)&Ab[((4 * 4 + q) * 16 + rxq) * 8];            \
    bf16x8 af5 = *(const bf16x8*)&Ab[((5 * 4 + q) * 16 + rxq) * 8];            \
    f32x4 az  = {bz, bz, bz, bz}, az2 = {0, 0, 0, 0};                          \
    f32x4 ac  = {bc, bc, bc, bc}, ac2 = {0, 0, 0, 0};                          \
    az  = MFMA(af0, wf[0][0], az,  0, 0, 0);                                   \
    az2 = MFMA(af1, wf[0][1], az2, 0, 0, 0);                                   \
    ac  = MFMA(af0, wf[1][0], ac,  0, 0, 0);                                   \
    ac2 = MFMA(af1, wf[1][1], ac2, 0, 0, 0);                                   \
    az  = MFMA(af2, wf[0][2], az,  0, 0, 0);                                   \
    az2 = MFMA(af3, wf[0][3], az2, 0, 0, 0);                                   \
    ac  = MFMA(af2, wf[1][2], ac,  0, 0, 0);                                   \
    ac2 = MFMA(af3, wf[1][3], ac2, 0, 0, 0);                                   \
    az  = MFMA(af4, wf[0][4], az,  0, 0, 0);                                   \
    az2 = MFMA(af5, wf[0][5], az2, 0, 0, 0);                                   \
    ac  = MFMA(af4, wf[1][4], ac,  0, 0, 0);                                   \
    ac2 = MFMA(af5, wf[1][5], ac2, 0, 0, 0);                                   \
    if (((PAR) ? (w < 4) : (w >= 4)) && t_ > 0) {                              \
      f32x4 ya = {bo_v, bo_v, bo_v, bo_v}, yb = {0, 0, 0, 0};                  \
      ya = MFMA(af2, wo[0], ya, 0, 0, 0);                                      \
      yb = MFMA(af3, wo[1], yb, 0, 0, 0);                                      \
      ya = MFMA(af4, wo[2], ya, 0, 0, 0);                                      \
      yb = MFMA(af5, wo[3], yb, 0, 0, 0);                                      \
      const int tm = t_ - 1;                                                   \
      _Pragma("unroll")                                                        \
      for (int i = 0; i < 4; i++) {                                            \
        if (lok[i] && tm < llen[i]) {                                          \
          float v = ya[i] + yb[i];                                             \
          yout[ybase[i] + tm * TDD] = v;                                       \
          ysum[i] += v; ysq[i] += v * v;                                       \
        }                                                                      \
      }                                                                        \
    }                                                                          \
    ushort hb[4];                                                              \
    _Pragma("unroll")                                                          \
    for (int i = 0; i < 4; i++) {                                              \
      float a_  = az[i] + az2[i];                                              \
      float b_  = ac[i] + ac2[i];                                              \
      float zv  = __builtin_amdgcn_rcpf(1.0f + __expf(-a_));                   \
      float hc  = 1.0f - 2.0f * __builtin_amdgcn_rcpf(1.0f + __expf(2.0f * b_)); \
      float h   = zv * hreg[i] + (1.0f - zv) * hc;                             \
      hreg[i] = (t_ < llen[i]) ? h : hreg[i];                                  \
      hb[i] = f2bf(hreg[i]);                                                   \
    }                                                                          \
    ushort* Aw = ldsA[(PAR) ^ 1];                                              \
    Aw[hwi[0]] = hb[0]; Aw[hwi[1]] = hb[1];                                    \
    Aw[hwi[2]] = hb[2]; Aw[hwi[3]] = hb[3];                                    \
    Aw[xa[0]] = f2bf(wx0);                                                     \
    Aw[xa[1]] = f2bf(wx1);                                                     \
    wx0 = sx0; wx1 = sx1; sx0 = tx0; sx1 = tx1; tx0 = nx0; tx1 = nx1;          \
    asm volatile("s_waitcnt lgkmcnt(0)" ::: "memory");                         \
    __builtin_amdgcn_s_barrier();                                              \
    __builtin_amdgcn_sched_barrier(0);                                         \
  }

  for (int t = 0; t < TT; t += 2) {
    STEP(t, 0)
    STEP(t + 1, 1)
  }
#undef STEP

  // epilogue: y_{TT-1}; h_{TT-1} frags are in buffer 0 (TT even), waves 4-7
  if (w >= 4) {
    const ushort* Ab = ldsA[0];
    bf16x8 ah0 = *(const bf16x8*)&Ab[((2 * 4 + q) * 16 + rxq) * 8];
    bf16x8 ah1 = *(const bf16x8*)&Ab[((3 * 4 + q) * 16 + rxq) * 8];
    bf16x8 ah2 = *(const bf16x8*)&Ab[((4 * 4 + q) * 16 + rxq) * 8];
    bf16x8 ah3 = *(const bf16x8*)&Ab[((5 * 4 + q) * 16 + rxq) * 8];
    f32x4 ya = {bo_v, bo_v, bo_v, bo_v}, yb = {0, 0, 0, 0};
    ya = MFMA(ah0, wo[0], ya, 0, 0, 0);
    yb = MFMA(ah1, wo[1], yb, 0, 0, 0);
    ya = MFMA(ah2, wo[2], ya, 0, 0, 0);
    yb = MFMA(ah3, wo[3], yb, 0, 0, 0);
    const int tm = TT - 1;
    #pragma unroll
    for (int i = 0; i < 4; i++) {
      if (lok[i] && tm < llen[i]) {
        float v = ya[i] + yb[i];
        yout[ybase[i] + tm * TDD] = v;
        ysum[i] += v; ysq[i] += v * v;
      }
    }
  }
  // flush masked per-channel stats (both parity groups hold partials)
  #pragma unroll
  for (int i = 0; i < 4; i++) {
    if (lok[i]) {
      atomicAdd(&wsStats[o * TDD + ld_[i]], ysum[i]);
      atomicAdd(&wsStats[ODCH + o * TDD + ld_[i]], ysq[i]);
    }
  }
}

// ---------------- BN finalize: per-channel scale/shift ------------------
__global__ __launch_bounds__(256) void finalize_kernel(
    const int* __restrict__ lengths, const float* __restrict__ gamma,
    const float* __restrict__ beta, float* __restrict__ wsStats)
{
  int ch = blockIdx.x * 256 + threadIdx.x;
  if (ch >= ODCH) return;
  int c = 0;
  #pragma unroll
  for (int b = 0; b < TB; b++) c += lengths[b];
  float inv = 1.0f / (float)c;
  float mean = wsStats[ch] * inv;
  float var = wsStats[ODCH + ch] * inv - mean * mean;
  float sc = rsqrtf(var + 1e-5f) * gamma[ch];
  wsStats[2 * ODCH + ch] = sc;
  wsStats[3 * ODCH + ch] = beta[ch] - mean * sc;
}

// ---------------- normalize (float4, scale/shift table) ------------------
__global__ __launch_bounds__(256) void norm_kernel(
    const int* __restrict__ lengths, const float* __restrict__ ss,
    float* __restrict__ out)
{
  int i4 = blockIdx.x * 256 + threadIdx.x;   // TOTAL/4 exact
  int idx = i4 * 4;
  float vv[4];
  *(float4*)vv = ((const float4*)out)[i4];
  int dq = idx / TDD; int d = idx - dq * TDD;
  int tq = dq / TT;   int tt = dq - tq * TT;
  int o = tq & 63;    int b = tq >> 6;
  float res[4];
  #pragma unroll
  for (int k = 0; k < 4; k++) {
    int ch = o * TDD + d;
    float r_ = 0.0f;
    if (tt < lengths[b])
      r_ = vv[k] * ss[ch] + ss[ODCH + ch];
    res[k] = r_;
    d++;
    if (d == TDD) { d = 0; tt++; if (tt == TT) { tt = 0; o++; if (o == 64) { o = 0; b++; } } }
  }
  ((float4*)out)[i4] = *(float4*)res;
}

extern "C" void kernel_launch(void* const* d_in, const int* in_sizes, int n_in,
                              void* d_out, int out_size, void* d_ws, size_t ws_size,
                              hipStream_t stream)
{
  const float* x       = (const float*)d_in[0];
  const int*   lengths = (const int*)d_in[1];
  const float* Wx      = (const float*)d_in[2];
  const float* Wh      = (const float*)d_in[3];
  const float* bias    = (const float*)d_in[4];
  const float* Wo      = (const float*)d_in[5];
  const float* bo      = (const float*)d_in[6];
  const float* gamma   = (const float*)d_in[7];
  const float* beta    = (const float*)d_in[8];
  float* out = (float*)d_out;
  float* wsStats = (float*)d_ws;   // 4*ODCH floats

  hipMemsetAsync(wsStats, 0, 2 * ODCH * sizeof(float), stream);
  hipLaunchKernelGGL(gru_kernel, dim3(NBLK), dim3(512), 0, stream,
                     x, lengths, Wx, Wh, bias, Wo, bo, out, wsStats);
  hipLaunchKernelGGL(finalize_kernel, dim3((ODCH + 255) / 256), dim3(256), 0, stream,
                     lengths, gamma, beta, wsStats);
  hipLaunchKernelGGL(norm_kernel, dim3(TOTAL / 4 / 256), dim3(256), 0, stream,
                     lengths, wsStats + 2 * ODCH, out);
}

// Round 6
// 303.397 us; speedup vs baseline: 1.8461x; 1.0236x over previous
//
#include <hip/hip_runtime.h>

#define TB 8
#define TC 64
#define TT 300
#define TDD 161
#define TH 128
#define TO 64
#define TN (TB * TDD)          // 1288 sequences
#define TWOH 256
#define TILE 16
#define NBLK 81                // ceil(1288/16)
#define NKS 6                  // (C+H)/32
#define ODCH (TO * TDD)        // 10304 channels
#define TOTAL (TB * TO * TT * TDD)      // 24729600
#define AFRAG (NKS * 4 * 16 * 8)        // 3072 ushorts per A-frag buffer

typedef __attribute__((ext_vector_type(8))) short bf16x8;
typedef __attribute__((ext_vector_type(4))) float f32x4;

#define MFMA __builtin_amdgcn_mfma_f32_16x16x32_bf16

__device__ __forceinline__ ushort f2bf(float f) {
  union { float f; unsigned u; } v; v.f = f;
  return (ushort)((v.u + 0x7fffu + ((v.u >> 16) & 1u)) >> 16);  // RNE
}

// k-mapping inside a 16x16x32 fragment; identical convention for A and B so
// any permutation error cancels in the contraction (verified R1/R2/R4).
__device__ __forceinline__ int kmap(int e, int q) {
  return ((e < 4) ? 0 : 16) + q * 4 + (e & 3);
}
// Swizzled ushort index of (row, kg) in the A-frag buffer (kg in [0,192)).
__device__ __forceinline__ int aidx_sw(int row, int kg) {
  int ks = kg >> 5, k32 = kg & 31;
  int half = k32 >> 4, qq = (k32 >> 2) & 3, em = k32 & 3;
  int B = (ks * 4 + qq) * 16 + (row ^ qq);
  return B * 8 + half * 4 + em;
}

__global__ __launch_bounds__(512) void gru_kernel(
    const float* __restrict__ x, const int* __restrict__ lengths,
    const float* __restrict__ Wx, const float* __restrict__ Wh,
    const float* __restrict__ bias, const float* __restrict__ Wo,
    const float* __restrict__ bo, float* __restrict__ yout,
    float* __restrict__ wsStats)
{
  __shared__ __align__(16) ushort ldsA[2][AFRAG];  // double-buffered [x_t | h] frags
  __shared__ float ytile[8][16 * 17 + 4];          // per-wave y transpose staging
  __shared__ int s_b[TILE], s_d[TILE], s_len[TILE], s_ok[TILE];

  const int tid = threadIdx.x;
  const int w = tid >> 6, l = tid & 63, q = l >> 4, r = l & 15;
  const int rxq = r ^ q;

  if (tid < TILE) {
    int n = blockIdx.x * TILE + tid;
    int ok = (n < TN) ? 1 : 0;
    int b = ok ? (n / TDD) : 0;
    int d = ok ? (n - b * TDD) : 0;
    s_b[tid] = b; s_d[tid] = d; s_ok[tid] = ok;
    s_len[tid] = ok ? lengths[b] : -1;
  }
  // zero the h-part (ushort idx >= 1024) of buffer 0 (h_{-1} = 0)
  for (int i = tid; i < AFRAG - 1024; i += 512) ldsA[0][1024 + i] = 0;
  __syncthreads();

  // ---- x loader mapping: thread -> (c = tid/8, nn = (tid%8)*2 + {0,1})
  const int xc = tid >> 3;
  const int xn0 = (tid & 7) * 2;
  int xok[2], xbase[2], xa[2];
  #pragma unroll
  for (int j = 0; j < 2; j++) {
    int nn = xn0 + j;
    xok[j] = s_ok[nn];
    xbase[j] = (s_b[nn] * TC + xc) * (TT * TDD) + s_d[nn];
    xa[j] = aidx_sw(nn, xc);
  }
  // x(0) into buffer 0; preload x(1..3) into the rotation (depth 4)
  #pragma unroll
  for (int j = 0; j < 2; j++) {
    float v = xok[j] ? x[xbase[j]] : 0.0f;
    ldsA[0][xa[j]] = f2bf(v);
  }
  float wx0 = xok[0] ? x[xbase[0] + 1 * TDD] : 0.0f;
  float wx1 = xok[1] ? x[xbase[1] + 1 * TDD] : 0.0f;
  float sx0 = xok[0] ? x[xbase[0] + 2 * TDD] : 0.0f;
  float sx1 = xok[1] ? x[xbase[1] + 2 * TDD] : 0.0f;
  float tx0 = xok[0] ? x[xbase[0] + 3 * TDD] : 0.0f;
  float tx1 = xok[1] ? x[xbase[1] + 3 * TDD] : 0.0f;

  // ---- gate B-fragments from [Wx; Wh] (registers, loaded once)
  bf16x8 wf[2][NKS];
  const int ucol = w * 16 + r;
  #pragma unroll
  for (int jj = 0; jj < 2; jj++) {
    int col = jj * TH + ucol;
    #pragma unroll
    for (int ks = 0; ks < NKS; ks++) {
      bf16x8 f;
      #pragma unroll
      for (int e = 0; e < 8; e++) {
        int kg = ks * 32 + kmap(e, q);
        float v = (kg < TC) ? Wx[kg * TWOH + col] : Wh[(kg - TC) * TWOH + col];
        f[e] = (short)f2bf(v);
      }
      wf[jj][ks] = f;
    }
  }
  const float bz = bias[ucol];
  const float bc = bias[TH + ucol];

  // ---- y B-frags (all 8 waves; groups alternate t-parity), o = (w&3)*16+r
  bf16x8 wo[4];
  #pragma unroll
  for (int ks = 0; ks < 4; ks++) {
    bf16x8 f;
    #pragma unroll
    for (int e = 0; e < 8; e++)
      f[e] = (short)f2bf(Wo[(ks * 32 + kmap(e, q)) * TO + ((w & 3) * 16 + r)]);
    wo[ks] = f;
  }
  const float bo_v = bo[(w & 3) * 16 + r];

  // gate-row info (rows nn = q*4+i)
  int llen[4];
  #pragma unroll
  for (int i = 0; i < 4; i++) llen[i] = s_len[q * 4 + i];

  // transposed-store info: lane handles n = l&15, o_j = (w&3)*16 + (l>>4) + 4j
  const int nT = l & 15;
  const int dT = s_d[nT], lenT = s_len[nT], okT = s_ok[nT];
  int ybaseT[4], ochT[4];
  #pragma unroll
  for (int j = 0; j < 4; j++) {
    int oj = (w & 3) * 16 + (l >> 4) + 4 * j;
    ybaseT[j] = (s_b[nT] * TO + oj) * (TT * TDD) + dT;
    ochT[j] = oj * TDD + dT;
  }
  float ysumT[4] = {0, 0, 0, 0}, ysqT[4] = {0, 0, 0, 0};

  float hreg[4] = {0, 0, 0, 0};
  int hwi[4];
  #pragma unroll
  for (int i = 0; i < 4; i++) hwi[i] = aidx_sw(q * 4 + i, TC + ucol);
  __syncthreads();

// y path: MFMA -> per-wave LDS tile (pad 17) -> same-wave transposed read ->
// coalesced store (4 segments/instr instead of 64-line scatter) + stats.
#define YPATH(TM_, A2, A3, A4, A5)                                             \
  {                                                                            \
    f32x4 ya = {bo_v, bo_v, bo_v, bo_v}, yb = {0, 0, 0, 0};                    \
    ya = MFMA(A2, wo[0], ya, 0, 0, 0);                                         \
    yb = MFMA(A3, wo[1], yb, 0, 0, 0);                                         \
    ya = MFMA(A4, wo[2], ya, 0, 0, 0);                                         \
    yb = MFMA(A5, wo[3], yb, 0, 0, 0);                                         \
    float* yt = &ytile[w][0];                                                  \
    _Pragma("unroll")                                                          \
    for (int i = 0; i < 4; i++) yt[r * 17 + q * 4 + i] = ya[i] + yb[i];        \
    const int tm = (TM_);                                                      \
    _Pragma("unroll")                                                          \
    for (int j = 0; j < 4; j++) {                                              \
      float v = yt[((l >> 4) + 4 * j) * 17 + nT];                              \
      if (okT) yout[ybaseT[j] + tm * TDD] = v;                                 \
      bool val = (tm < lenT);                                                  \
      ysumT[j] += val ? v : 0.0f;                                              \
      ysqT[j]  += val ? v * v : 0.0f;                                          \
    }                                                                          \
  }

#define STEP(T_, PAR)                                                          \
  {                                                                            \
    const int t_ = (T_);                                                       \
    int tc = t_ + 4; tc = (tc < TT) ? tc : (TT - 1);                           \
    float nx0 = xok[0] ? x[xbase[0] + tc * TDD] : 0.0f;                        \
    float nx1 = xok[1] ? x[xbase[1] + tc * TDD] : 0.0f;                        \
    const ushort* Ab = ldsA[PAR];                                              \
    bf16x8 af0 = *(const bf16x8*)&Ab[((0 * 4 + q) * 16 + rxq) * 8];            \
    bf16x8 af1 = *(const bf16x8*)&Ab[((1 * 4 + q) * 16 + rxq) * 8];            \
    bf16x8 af2 = *(const bf16x8*)&Ab[((2 * 4 + q) * 16 + rxq) * 8];            \
    bf16x8 af3 = *(const bf16x8*)&Ab[((3 * 4 + q) * 16 + rxq) * 8];            \
    bf16x8 af4 = *(const bf16x8*)&Ab[((4 * 4 + q) * 16 + rxq) * 8];            \
    bf16x8 af5 = *(const bf16x8*)&Ab[((5 * 4 + q) * 16 + rxq) * 8];            \
    f32x4 az  = {bz, bz, bz, bz}, az2 = {0, 0, 0, 0};                          \
    f32x4 ac  = {bc, bc, bc, bc}, ac2 = {0, 0, 0, 0};                          \
    az  = MFMA(af0, wf[0][0], az,  0, 0, 0);                                   \
    az2 = MFMA(af1, wf[0][1], az2, 0, 0, 0);                                   \
    ac  = MFMA(af0, wf[1][0], ac,  0, 0, 0);                                   \
    ac2 = MFMA(af1, wf[1][1], ac2, 0, 0, 0);                                   \
    az  = MFMA(af2, wf[0][2], az,  0, 0, 0);                                   \
    az2 = MFMA(af3, wf[0][3], az2, 0, 0, 0);                                   \
    ac  = MFMA(af2, wf[1][2], ac,  0, 0, 0);                                   \
    ac2 = MFMA(af3, wf[1][3], ac2, 0, 0, 0);                                   \
    az  = MFMA(af4, wf[0][4], az,  0, 0, 0);                                   \
    az2 = MFMA(af5, wf[0][5], az2, 0, 0, 0);                                   \
    ac  = MFMA(af4, wf[1][4], ac,  0, 0, 0);                                   \
    ac2 = MFMA(af5, wf[1][5], ac2, 0, 0, 0);                                   \
    if (((PAR) ? (w < 4) : (w >= 4)) && t_ > 0) {                              \
      YPATH(t_ - 1, af2, af3, af4, af5)                                        \
    }                                                                          \
    ushort hb[4];                                                              \
    _Pragma("unroll")                                                          \
    for (int i = 0; i < 4; i++) {                                              \
      float a_  = az[i] + az2[i];                                              \
      float b_  = ac[i] + ac2[i];                                              \
      float zv  = __builtin_amdgcn_rcpf(1.0f + __expf(-a_));                   \
      float hc  = 1.0f - 2.0f * __builtin_amdgcn_rcpf(1.0f + __expf(2.0f * b_)); \
      float h   = zv * hreg[i] + (1.0f - zv) * hc;                             \
      hreg[i] = (t_ < llen[i]) ? h : hreg[i];                                  \
      hb[i] = f2bf(hreg[i]);                                                   \
    }                                                                          \
    ushort* Aw = ldsA[(PAR) ^ 1];                                              \
    Aw[hwi[0]] = hb[0]; Aw[hwi[1]] = hb[1];                                    \
    Aw[hwi[2]] = hb[2]; Aw[hwi[3]] = hb[3];                                    \
    Aw[xa[0]] = f2bf(wx0);                                                     \
    Aw[xa[1]] = f2bf(wx1);                                                     \
    wx0 = sx0; wx1 = sx1; sx0 = tx0; sx1 = tx1; tx0 = nx0; tx1 = nx1;          \
    asm volatile("s_waitcnt lgkmcnt(0)" ::: "memory");                         \
    __builtin_amdgcn_s_barrier();                                              \
    __builtin_amdgcn_sched_barrier(0);                                         \
  }

  for (int t = 0; t < TT; t += 2) {
    STEP(t, 0)
    STEP(t + 1, 1)
  }
#undef STEP

  // epilogue: y_{TT-1}; h_{TT-1} frags are in buffer 0 (TT even), waves 4-7
  if (w >= 4) {
    const ushort* Ab = ldsA[0];
    bf16x8 ah0 = *(const bf16x8*)&Ab[((2 * 4 + q) * 16 + rxq) * 8];
    bf16x8 ah1 = *(const bf16x8*)&Ab[((3 * 4 + q) * 16 + rxq) * 8];
    bf16x8 ah2 = *(const bf16x8*)&Ab[((4 * 4 + q) * 16 + rxq) * 8];
    bf16x8 ah3 = *(const bf16x8*)&Ab[((5 * 4 + q) * 16 + rxq) * 8];
    YPATH(TT - 1, ah0, ah1, ah2, ah3)
  }
#undef YPATH

  // flush masked per-channel stats (both parity groups hold partials)
  #pragma unroll
  for (int j = 0; j < 4; j++) {
    if (okT) {
      atomicAdd(&wsStats[ochT[j]], ysumT[j]);
      atomicAdd(&wsStats[ODCH + ochT[j]], ysqT[j]);
    }
  }
}

// ---------------- BN finalize: per-channel scale/shift ------------------
__global__ __launch_bounds__(256) void finalize_kernel(
    const int* __restrict__ lengths, const float* __restrict__ gamma,
    const float* __restrict__ beta, float* __restrict__ wsStats)
{
  int ch = blockIdx.x * 256 + threadIdx.x;
  if (ch >= ODCH) return;
  int c = 0;
  #pragma unroll
  for (int b = 0; b < TB; b++) c += lengths[b];
  float inv = 1.0f / (float)c;
  float mean = wsStats[ch] * inv;
  float var = wsStats[ODCH + ch] * inv - mean * mean;
  float sc = rsqrtf(var + 1e-5f) * gamma[ch];
  wsStats[2 * ODCH + ch] = sc;
  wsStats[3 * ODCH + ch] = beta[ch] - mean * sc;
}

// ---------------- normalize (float4, scale/shift table) ------------------
__global__ __launch_bounds__(256) void norm_kernel(
    const int* __restrict__ lengths, const float* __restrict__ ss,
    float* __restrict__ out)
{
  int i4 = blockIdx.x * 256 + threadIdx.x;   // TOTAL/4 exact
  int idx = i4 * 4;
  float vv[4];
  *(float4*)vv = ((const float4*)out)[i4];
  int dq = idx / TDD; int d = idx - dq * TDD;
  int tq = dq / TT;   int tt = dq - tq * TT;
  int o = tq & 63;    int b = tq >> 6;
  float res[4];
  #pragma unroll
  for (int k = 0; k < 4; k++) {
    int ch = o * TDD + d;
    float r_ = 0.0f;
    if (tt < lengths[b])
      r_ = vv[k] * ss[ch] + ss[ODCH + ch];
    res[k] = r_;
    d++;
    if (d == TDD) { d = 0; tt++; if (tt == TT) { tt = 0; o++; if (o == 64) { o = 0; b++; } } }
  }
  ((float4*)out)[i4] = *(float4*)res;
}

extern "C" void kernel_launch(void* const* d_in, const int* in_sizes, int n_in,
                              void* d_out, int out_size, void* d_ws, size_t ws_size,
                              hipStream_t stream)
{
  const float* x       = (const float*)d_in[0];
  const int*   lengths = (const int*)d_in[1];
  const float* Wx      = (const float*)d_in[2];
  const float* Wh      = (const float*)d_in[3];
  const float* bias    = (const float*)d_in[4];
  const float* Wo      = (const float*)d_in[5];
  const float* bo      = (const float*)d_in[6];
  const float* gamma   = (const float*)d_in[7];
  const float* beta    = (const float*)d_in[8];
  float* out = (float*)d_out;
  float* wsStats = (float*)d_ws;   // 4*ODCH floats

  hipMemsetAsync(wsStats, 0, 2 * ODCH * sizeof(float), stream);
  hipLaunchKernelGGL(gru_kernel, dim3(NBLK), dim3(512), 0, stream,
                     x, lengths, Wx, Wh, bias, Wo, bo, out, wsStats);
  hipLaunchKernelGGL(finalize_kernel, dim3((ODCH + 255) / 256), dim3(256), 0, stream,
                     lengths, gamma, beta, wsStats);
  hipLaunchKernelGGL(norm_kernel, dim3(TOTAL / 4 / 256), dim3(256), 0, stream,
                     lengths, wsStats + 2 * ODCH, out);
}